// Round 12
// baseline (1144.897 us; speedup 1.0000x reference)
//
#include <hip/hip_runtime.h>

#define VOCAB 50257
#define EMB 256
#define HID 512
#define BATCH 32
#define SEQ 512

typedef _Float16 h2 __attribute__((ext_vector_type(2)));
typedef unsigned int u32;

#if __has_builtin(__builtin_amdgcn_fdot2)
#define FDOT2(a, b, c) __builtin_amdgcn_fdot2((a), (b), (c), false)
#else
static __device__ __forceinline__ float FDOT2(h2 a, h2 b, float c) {
    return c + (float)a.x * (float)b.x + (float)a.y * (float)b.y;
}
#endif

// lgkm-only barrier: orders LDS traffic without draining vmcnt.
#define LBAR() do {                                            \
    asm volatile("s_waitcnt lgkmcnt(0)" ::: "memory");         \
    __builtin_amdgcn_s_barrier();                              \
    asm volatile("" ::: "memory");                             \
} while (0)

static __device__ __forceinline__ h2 mk2(float a, float b) {
    h2 r; r.x = (_Float16)a; r.y = (_Float16)b; return r;   // RTN converts
}
static __device__ __forceinline__ u32 pk_rtn(float a, float b) {
    return __builtin_bit_cast(u32, mk2(a, b));
}
static __device__ __forceinline__ h2 as_h2(u32 v) {
    return __builtin_bit_cast(h2, v);
}

// ---------------------------------------------------------------------------
// K1: X[tok][j] = bias[j] + emb[ids[tok]] @ Wx[:,j] -> all_h region of d_out.
// ---------------------------------------------------------------------------
__global__ __launch_bounds__(256) void xprec_kernel(
    const int* __restrict__ ids, const float* __restrict__ emb,
    const float* __restrict__ Wx, const float* __restrict__ bias,
    float* __restrict__ allh)
{
    __shared__ float embL[32][EMB];   // 32 KB
    const int tid  = threadIdx.x;
    const int tok0 = blockIdx.x * 32;

    {
        const int t    = tid >> 3;
        const int part = tid & 7;
        const int id   = ids[tok0 + t];
        const float4* src = (const float4*)(emb + (size_t)id * EMB + part * 32);
        float4* dst = (float4*)(&embL[t][part * 32]);
#pragma unroll
        for (int k = 0; k < 8; ++k) dst[k] = src[k];
    }
    __syncthreads();

    const int j0 = tid * 2;
    float2 acc[32];
    const float2 bv = *(const float2*)(bias + j0);
#pragma unroll
    for (int t = 0; t < 32; ++t) acc[t] = bv;

    for (int e = 0; e < EMB; e += 4) {
        const float2 w0 = *(const float2*)(Wx + (size_t)(e + 0) * HID + j0);
        const float2 w1 = *(const float2*)(Wx + (size_t)(e + 1) * HID + j0);
        const float2 w2 = *(const float2*)(Wx + (size_t)(e + 2) * HID + j0);
        const float2 w3 = *(const float2*)(Wx + (size_t)(e + 3) * HID + j0);
#pragma unroll
        for (int t = 0; t < 32; ++t) {
            const float4 ev = *(const float4*)(&embL[t][e]);
            acc[t].x += ev.x * w0.x + ev.y * w1.x + ev.z * w2.x + ev.w * w3.x;
            acc[t].y += ev.x * w0.y + ev.y * w1.y + ev.z * w2.y + ev.w * w3.y;
        }
    }

#pragma unroll
    for (int t = 0; t < 32; ++t) {
        *(float2*)(allh + (size_t)(tok0 + t) * HID + j0) = acc[t];
    }
}

// ---------------------------------------------------------------------------
// K2: one WG per batch, 1024 threads = 16 waves = 4 waves/SIMD.
// __launch_bounds__(1024,4) -> 128-reg budget -> all true VGPRs (no AGPR).
// Thread (c=tid&63, p=tid>>6): kp=p&7 -> k-window [64kp,64kp+64) (32 pairs);
// ch=p>>3 -> cols {64*(4ch+q')+c, q'=0..3}. q'=0..2 in regs (96 h2),
// q'=3 in LDS (wl, 128 KB, 8 ds_read_b128/thread/step).
// h: packed pairs in hbuf (1 KB); 1 b32 read + 32 readlanes per thread.
// Partials: zpp (8 kgroups, packed pairs) -> tid<512 reduces col tid.
// 2 lgkm-only barriers per step.
// ---------------------------------------------------------------------------
__global__ __launch_bounds__(1024, 4) void rnn_local_kernel(
    const int* __restrict__ mask, const float* __restrict__ Wh,
    float* __restrict__ allh, float* __restrict__ finalh)
{
    __shared__ uint4 wl[8][1024];          // 128 KB: weight group q'=3
    __shared__ u32   zpp[8][2][2][64];     // 8 KB: [kg][ch][pairidx][c]
    __shared__ u32   hbuf[256];            // 1 KB: packed h pairs
    __shared__ unsigned short mlist[SEQ];  // 1 KB
    __shared__ int   nmL;

    const int tid = threadIdx.x;
    const int b   = blockIdx.x;
    const int c   = tid & 63;
    const int p   = tid >> 6;
    const int kp  = p & 7;       // k-window [64kp, 64kp+64)
    const int ch  = p >> 3;      // column half (q = 4ch + q')

    // ---- mask compaction (stage in zpp's storage; zpp unused yet) ----
    int* maskL = (int*)zpp;
    if (tid < SEQ) maskL[tid] = mask[b * SEQ + tid];
    __syncthreads();
    if (tid == 0) {
        int n = 0;
        for (int t = 0; t < SEQ; ++t) if (maskL[t]) mlist[n++] = (unsigned short)t;
        nmL = n;
    }

    // ---- weights: q'=0..2 into regs, q'=3 into LDS ----
    const float* wb = Wh + (size_t)(64 * kp) * HID + (256 * ch + c);
    h2 wA[32], wB[32], wC[32];
#pragma unroll 4
    for (int m = 0; m < 32; ++m) {
        const float* r0 = wb + (size_t)(2 * m) * HID;
        const float* r1 = r0 + HID;
        wA[m] = mk2(r0[0],   r1[0]);
        wB[m] = mk2(r0[64],  r1[64]);
        wC[m] = mk2(r0[128], r1[128]);
    }
#pragma unroll
    for (int u = 0; u < 8; ++u) {
        uint4 v; u32* vp = (u32*)&v;
#pragma unroll
        for (int e = 0; e < 4; ++e) {
            const float* r0 = wb + (size_t)(8 * u + 2 * e) * HID;
            const float* r1 = r0 + HID;
            vp[e] = pk_rtn(r0[192], r1[192]);
        }
        wl[u][tid] = v;
    }
    if (tid < 256) hbuf[tid] = 0u;     // h = 0
    __syncthreads();
    const int nm = nmL;

    float* arow = allh + (size_t)b * SEQ * HID;

    // rows before the first masked step carry h = 0 (cols by tid<512)
    {
        const int end0 = nm ? mlist[0] : SEQ;
        if (tid < 512)
            for (int t = 0; t < end0; ++t) arow[(size_t)t * HID + tid] = 0.f;
    }

    float hreg = 0.f, xnext = 0.f;
    if (nm && tid < 512) xnext = arow[(size_t)mlist[0] * HID + tid];

    for (int it = 0; it < nm; ++it) {
        const int t    = mlist[it];
        const int tend = (it + 1 < nm) ? mlist[it + 1] : SEQ;
        const float x  = xnext;
        if (tid < 512 && it + 1 < nm)     // prefetch next X; retires in bkgnd
            xnext = arow[(size_t)mlist[it + 1] * HID + tid];

        // lane's h pair: window pair (c&31) -> lanes 0..31 hold pairs 0..31
        const u32 pku = hbuf[32 * kp + (c & 31)];

        float a0 = 0.f, a1 = 0.f, a2 = 0.f, a3 = 0.f;
#pragma unroll
        for (int u = 0; u < 8; ++u) {
            const uint4 wt = wl[u][tid];          // ds_read_b128
            const u32* wp = (const u32*)&wt;
#pragma unroll
            for (int e = 0; e < 4; ++e) {
                const int m = 4 * u + e;
                const h2 hv = as_h2((u32)__builtin_amdgcn_readlane((int)pku, m));
                a0 = FDOT2(wA[m], hv, a0);
                a1 = FDOT2(wB[m], hv, a1);
                a2 = FDOT2(wC[m], hv, a2);
                a3 = FDOT2(as_h2(wp[e]), hv, a3);
            }
        }
        zpp[kp][ch][0][c] = pk_rtn(a0, a1);   // cols 4ch+0, 4ch+1
        zpp[kp][ch][1][c] = pk_rtn(a2, a3);   // cols 4ch+2, 4ch+3
        LBAR();                                // zpp visible

        if (tid < 512) {                       // col j = tid
            const int q  = tid >> 6;           // j = 64q + c
            const int qh = q >> 2, qe = (q >> 1) & 1, qs = q & 1;
            float z = 0.f;
#pragma unroll
            for (int kg = 0; kg < 8; ++kg) {
                const h2 pr = as_h2(zpp[kg][qh][qe][c]);
                z += (float)(qs ? pr.y : pr.x);   // wave-uniform select
            }
            const float hn = tanhf(x + z);
            hreg = hn;
            for (int tt = t; tt < tend; ++tt)     // fire-and-forget stores
                arow[(size_t)tt * HID + tid] = hn;
            const float hp = __shfl_xor(hn, 1);
            if ((tid & 1) == 0) hbuf[tid >> 1] = pk_rtn(hn, hp);
        }
        LBAR();                                // hbuf ready; zpp reads done
    }
    if (tid < 512) finalh[b * HID + tid] = hreg;
}

extern "C" void kernel_launch(void* const* d_in, const int* in_sizes, int n_in,
                              void* d_out, int out_size, void* d_ws, size_t ws_size,
                              hipStream_t stream) {
    const int*   ids  = (const int*)d_in[0];
    const int*   msk  = (const int*)d_in[1];
    const float* emb  = (const float*)d_in[2];
    const float* Wx   = (const float*)d_in[3];
    const float* Wh   = (const float*)d_in[4];
    const float* bias = (const float*)d_in[5];

    float* allh   = (float*)d_out;                              // [B*S][H]
    float* finalh = (float*)d_out + (size_t)BATCH * SEQ * HID;  // [B][H]

    xprec_kernel<<<BATCH * SEQ / 32, 256, 0, stream>>>(ids, emb, Wx, bias, allh);
    rnn_local_kernel<<<BATCH, 1024, 0, stream>>>(msk, Wh, allh, finalh);
}